// Round 20
// baseline (61.616 us; speedup 1.0000x reference)
//
#include <hip/hip_runtime.h>
#include <hip/hip_bf16.h>
#include <math.h>

#define DD 32
#define HH 128

typedef __attribute__((ext_vector_type(8))) __bf16 bf16x8;
typedef __attribute__((ext_vector_type(4))) float  f32x4;

// ---- ws layout (float offsets) -------------------------------------------
// [0,192)        tripg : 6 x 32 raw triple gradients
// [192,200)      tripS : 6 src row indices (int view)
// [224,352)      c0    : vb1[kh] + t * vW1[32][kh]
// [384,16768)    frags : 64 frags, lane-major (frag*64+lane)*4 floats (64KB)
//                 order: s-blocks of 8 (net1: frags s*8+0..7; net2: 32+s*8+0..7)
//                 within block: [AH(2s) AL(2s) AH(2s+1) AL(2s+1)
//                                BH(nt0) BL(nt0) BH(nt1) BL(nt1)]
// [16768,+npart) partner
#define WS_TRIPG 0
#define WS_TRIPS 192
#define WS_C0    224
#define WS_FRAG  384
#define WS_PART  16768

#define ENC_ZF  0x40000000u
#define ENC_SEC 0x80000000u

union b8u { bf16x8 v; uint32_t u[4]; };

__device__ __forceinline__ f32x4 mfma16(bf16x8 a, bf16x8 b, f32x4 c) {
    return __builtin_amdgcn_mfma_f32_16x16x32_bf16(a, b, c, 0, 0, 0);
}

// ---- primitives (exact R14 set — proven pass) -----------------------------
__device__ __forceinline__ uint32_t cvtpk(float a, float b) {
    uint32_t r;
    asm("v_cvt_pk_bf16_f32 %0, %1, %2" : "=v"(r) : "v"(a), "v"(b));
    return r;
}
__device__ __forceinline__ float vexp2(float x) {   // 2^x
    float r; asm("v_exp_f32 %0, %1" : "=v"(r) : "v"(x)); return r;
}
__device__ __forceinline__ float vrcp(float x) {    // 1/x approx
    float r; asm("v_rcp_f32 %0, %1" : "=v"(r) : "v"(x)); return r;
}

__device__ __forceinline__ void split2a(float a, float b,
                                        uint32_t& h, uint32_t& l) {
    h = cvtpk(a, b);
    float af = __uint_as_float(h << 16);
    float bf = __uint_as_float(h & 0xffff0000u);
    l = cvtpk(a - af, b - bf);
}

#define TWO_LOG2E 2.8853900817779268f   // e^{2x} = 2^{x*TWO_LOG2E}

__device__ __forceinline__ float tanh_fast(float x) {   // 1 - 2/(e^{2x}+1)
    float e = vexp2(x * TWO_LOG2E);
    float q = 2.0f * vrcp(e + 1.0f);
    return 1.0f - q;
}
__device__ __forceinline__ float wsech2(float w, float x) { // w*q*(2-q)
    float e = vexp2(x * TWO_LOG2E);
    float q = 2.0f * vrcp(e + 1.0f);
    return w * (q * (2.0f - q));
}

// prep-only split (runs once)
__device__ __forceinline__ void split2(float a, float b,
                                       uint32_t& h, uint32_t& l) {
    __hip_bfloat162 hb = __float22bfloat162_rn(make_float2(a, b));
    uint32_t hu; __builtin_memcpy(&hu, &hb, 4);
    float af = __uint_as_float(hu << 16);
    float bf = __uint_as_float(hu & 0xffff0000u);
    __hip_bfloat162 lb = __float22bfloat162_rn(make_float2(a - af, b - bf));
    uint32_t lu; __builtin_memcpy(&lu, &lb, 4);
    h = hu; l = lu;
}

// ---- Prep 1: c0 + frag table (identical to R14) ---------------------------
__global__ void k_prep(const float* __restrict__ t,
                       const float* __restrict__ vW1,  // (33,128)
                       const float* __restrict__ vb1,  // (128)
                       const float* __restrict__ vW2,  // (128,32)
                       const float* __restrict__ pW1,  // (32,128)
                       float* __restrict__ ws)
{
    int tid = blockIdx.x * 256 + threadIdx.x;
    if (tid < 4096) {
        int f = tid >> 6, lane = tid & 63;
        int g = lane >> 4, m = lane & 15;
        int reg  = f >> 5;          // 0:net1  1:net2
        int s    = (f >> 3) & 3;
        int slot = f & 7;
        bool isLo = slot & 1;
        float v[8];
        if (slot < 4) {             // A-operand (vW1 / pW1), th = 2s+(slot>>1)
            const float* W = reg ? pW1 : vW1;
            int th = 2 * s + (slot >> 1);
            #pragma unroll
            for (int i = 0; i < 8; i++)
                v[i] = W[(8 * g + i) * HH + 16 * th + m];
        } else {                    // B-operand, nt = (slot-4)>>1
            int nt = (slot - 4) >> 1;
            #pragma unroll
            for (int i = 0; i < 8; i++) {
                int kh = 16 * (2 * s + (i >> 2)) + 4 * g + (i & 3);
                v[i] = reg ? pW1[(nt * 16 + m) * HH + kh]
                           : vW2[kh * DD + nt * 16 + m];
            }
        }
        b8u H, L;
        #pragma unroll
        for (int j = 0; j < 4; j++)
            split2(v[2 * j], v[2 * j + 1], H.u[j], L.u[j]);
        *(f32x4*)(ws + WS_FRAG + (size_t)(f * 64 + lane) * 4) =
            isLo ? *(f32x4*)&L : *(f32x4*)&H;
    } else if (tid < 4096 + HH) {
        int k = tid - 4096;
        ws[WS_C0 + k] = vb1[k] + t[0] * vW1[DD * HH + k];
    }
}

// ---- Prep 2: row-centric partner[] (identical to R14) ---------------------
__global__ void k_prep2(const int* __restrict__ perm,
                        unsigned int* __restrict__ partner,
                        int* __restrict__ tripS,
                        int np, int ntr, int B, int npart)
{
    int j = blockIdx.x * 256 + threadIdx.x;
    if (j < np) {
        int a = perm[2 * j], b = perm[2 * j + 1];
        partner[a] = (unsigned int)b;
        partner[b] = (unsigned int)a | ENC_SEC;
    }
    if (j == 0) {
        int base = B;
        if (ntr) {
            for (int i = 0; i < 3; i++)
                partner[perm[2 * np + i]] = ENC_ZF;
            for (int ti = 0; ti < 6; ti++) {
                int i3 = ti >> 1, r3 = ti & 1;
                int j3 = r3 + ((r3 >= i3) ? 1 : 0);
                tripS[ti] = perm[2 * np + i3];
                partner[B + ti] = (unsigned int)perm[2 * np + j3];
            }
            base = B + 6;
        }
        for (int q = base; q < npart; q++) partner[q] = ENC_ZF;
    }
}

// ---- Main: R14 body, but frag table staged in LDS by persistent blocks ----
// Each block copies the 64KB frag table to LDS once, then loops over tiles.
// Per-tile math is bit-identical to R14 (passing, 53.9us).
__global__ __launch_bounds__(256) void k_main(
    const float* __restrict__ z,
    const float* __restrict__ ws,
    const unsigned int* __restrict__ partner,
    const float* __restrict__ vb2,
    const float* __restrict__ pb1,
    const float* __restrict__ pW2,
    float* __restrict__ out,
    float* __restrict__ tripg,
    int B, int ntiles)
{
    __shared__ float sfr[64 * 256];     // 64 KB: frag f at sfr[f*256 + lane*4]

    // cooperative copy: 4096 f32x4 elements, 256 threads, 16 iters
    {
        const f32x4* src = (const f32x4*)(ws + WS_FRAG);
        f32x4*       dst = (f32x4*)sfr;
        for (int i = threadIdx.x; i < 4096; i += 256) dst[i] = src[i];
    }
    __syncthreads();

    int lane = threadIdx.x & 63;
    int wid  = blockIdx.x * 4 + (threadIdx.x >> 6);
    int nw   = gridDim.x * 4;
    int g = lane >> 4, m = lane & 15;
    const int* tripS = (const int*)(ws + WS_TRIPS);
    float vb20 = vb2[m], vb21 = vb2[16 + m];

    for (int tt = wid; tt < ntiles; tt += nw) {
        int rbase = tt * 32;
        int il0 = rbase + m, il1 = rbase + 16 + m;

        unsigned int e0 = partner[il0];
        unsigned int e1 = partner[il1];
        int pi0 = (int)(e0 & 0x3FFFFFFFu);
        int pi1 = (int)(e1 & 0x3FFFFFFFu);
        int is0 = il0, is1 = il1;
        if (il0 >= B) { int ti = il0 - B; is0 = (ti < 6) ? tripS[ti] : 0; }
        if (il1 >= B) { int ti = il1 - B; is1 = (ti < 6) ? tripS[ti] : 0; }
        float fs0 = (e0 & ENC_ZF) ? 0.f : ((e0 & ENC_SEC) ? 1.f : -1.f);
        float fs1 = (e1 & ENC_ZF) ? 0.f : ((e1 & ENC_SEC) ? 1.f : -1.f);

        // issue all 8 z loads up front
        const float* pz0 = z + (size_t)is0 * DD + 8 * g;
        const float* pp0 = z + (size_t)pi0 * DD + 8 * g;
        const float* pz1 = z + (size_t)is1 * DD + 8 * g;
        const float* pp1 = z + (size_t)pi1 * DD + 8 * g;
        f32x4 zi00 = *(const f32x4*)pz0, zi01 = *(const f32x4*)(pz0 + 4);
        f32x4 zp00 = *(const f32x4*)pp0, zp01 = *(const f32x4*)(pp0 + 4);
        f32x4 zi10 = *(const f32x4*)pz1, zi11 = *(const f32x4*)(pz1 + 4);
        f32x4 zp10 = *(const f32x4*)pp1, zp11 = *(const f32x4*)(pp1 + 4);

        b8u Z0H, Z0L, D0H, D0L, Z1H, Z1L, D1H, D1L;
        split2a(zi00[0], zi00[1], Z0H.u[0], Z0L.u[0]);
        split2a(zi00[2], zi00[3], Z0H.u[1], Z0L.u[1]);
        split2a(zi01[0], zi01[1], Z0H.u[2], Z0L.u[2]);
        split2a(zi01[2], zi01[3], Z0H.u[3], Z0L.u[3]);
        split2a(zi10[0], zi10[1], Z1H.u[0], Z1L.u[0]);
        split2a(zi10[2], zi10[3], Z1H.u[1], Z1L.u[1]);
        split2a(zi11[0], zi11[1], Z1H.u[2], Z1L.u[2]);
        split2a(zi11[2], zi11[3], Z1H.u[3], Z1L.u[3]);
        {
            float d0, d1;
            d0 = -fs0 * (zi00[0] - zp00[0]); d1 = -fs0 * (zi00[1] - zp00[1]);
            split2a(d0, d1, D0H.u[0], D0L.u[0]);
            d0 = -fs0 * (zi00[2] - zp00[2]); d1 = -fs0 * (zi00[3] - zp00[3]);
            split2a(d0, d1, D0H.u[1], D0L.u[1]);
            d0 = -fs0 * (zi01[0] - zp01[0]); d1 = -fs0 * (zi01[1] - zp01[1]);
            split2a(d0, d1, D0H.u[2], D0L.u[2]);
            d0 = -fs0 * (zi01[2] - zp01[2]); d1 = -fs0 * (zi01[3] - zp01[3]);
            split2a(d0, d1, D0H.u[3], D0L.u[3]);
            d0 = -fs1 * (zi10[0] - zp10[0]); d1 = -fs1 * (zi10[1] - zp10[1]);
            split2a(d0, d1, D1H.u[0], D1L.u[0]);
            d0 = -fs1 * (zi10[2] - zp10[2]); d1 = -fs1 * (zi10[3] - zp10[3]);
            split2a(d0, d1, D1H.u[1], D1L.u[1]);
            d0 = -fs1 * (zi11[0] - zp11[0]); d1 = -fs1 * (zi11[1] - zp11[1]);
            split2a(d0, d1, D1H.u[2], D1L.u[2]);
            d0 = -fs1 * (zi11[2] - zp11[2]); d1 = -fs1 * (zi11[3] - zp11[3]);
            split2a(d0, d1, D1H.u[3], D1L.u[3]);
        }

        // ---- net1: dz_dt (frags from LDS) ----------------------------------
        f32x4 av00 = (f32x4){vb20, vb20, vb20, vb20};
        f32x4 av01 = (f32x4){vb21, vb21, vb21, vb21};
        f32x4 av10 = av00, av11 = av01;
        {
            const float* cg = ws + WS_C0 + 4 * g;
            int fb0 = lane * 4;                 // net1 frag base in sfr
            #pragma unroll 1
            for (int s = 0; s < 4; s++) {
                int sb = fb0 + s * 8 * 256;
                bf16x8 w1h0 = *(const bf16x8*)&sfr[sb + 0 * 256];
                bf16x8 w1l0 = *(const bf16x8*)&sfr[sb + 1 * 256];
                bf16x8 w1h1 = *(const bf16x8*)&sfr[sb + 2 * 256];
                bf16x8 w1l1 = *(const bf16x8*)&sfr[sb + 3 * 256];
                f32x4 c0v = *(const f32x4*)(cg + 32 * s);
                f32x4 c1v = *(const f32x4*)(cg + 32 * s + 16);
                f32x4 u00 = c0v, u01 = c1v, u10 = c0v, u11 = c1v;
                u00 = mfma16(w1h0, Z0L.v, u00); u00 = mfma16(w1l0, Z0H.v, u00); u00 = mfma16(w1h0, Z0H.v, u00);
                u01 = mfma16(w1h1, Z0L.v, u01); u01 = mfma16(w1l1, Z0H.v, u01); u01 = mfma16(w1h1, Z0H.v, u01);
                u10 = mfma16(w1h0, Z1L.v, u10); u10 = mfma16(w1l0, Z1H.v, u10); u10 = mfma16(w1h0, Z1H.v, u10);
                u11 = mfma16(w1h1, Z1L.v, u11); u11 = mfma16(w1l1, Z1H.v, u11); u11 = mfma16(w1h1, Z1H.v, u11);
                b8u A0H, A0L, A1H, A1L;
                split2a(tanh_fast(u00[0]), tanh_fast(u00[1]), A0H.u[0], A0L.u[0]);
                split2a(tanh_fast(u00[2]), tanh_fast(u00[3]), A0H.u[1], A0L.u[1]);
                split2a(tanh_fast(u01[0]), tanh_fast(u01[1]), A0H.u[2], A0L.u[2]);
                split2a(tanh_fast(u01[2]), tanh_fast(u01[3]), A0H.u[3], A0L.u[3]);
                split2a(tanh_fast(u10[0]), tanh_fast(u10[1]), A1H.u[0], A1L.u[0]);
                split2a(tanh_fast(u10[2]), tanh_fast(u10[3]), A1H.u[1], A1L.u[1]);
                split2a(tanh_fast(u11[0]), tanh_fast(u11[1]), A1H.u[2], A1L.u[2]);
                split2a(tanh_fast(u11[2]), tanh_fast(u11[3]), A1H.u[3], A1L.u[3]);
                bf16x8 b0h = *(const bf16x8*)&sfr[sb + 4 * 256];
                bf16x8 b0l = *(const bf16x8*)&sfr[sb + 5 * 256];
                bf16x8 b1h = *(const bf16x8*)&sfr[sb + 6 * 256];
                bf16x8 b1l = *(const bf16x8*)&sfr[sb + 7 * 256];
                av00 = mfma16(A0H.v, b0l, av00); av00 = mfma16(A0L.v, b0h, av00); av00 = mfma16(A0H.v, b0h, av00);
                av01 = mfma16(A0H.v, b1l, av01); av01 = mfma16(A0L.v, b1h, av01); av01 = mfma16(A0H.v, b1h, av01);
                av10 = mfma16(A1H.v, b0l, av10); av10 = mfma16(A1L.v, b0h, av10); av10 = mfma16(A1H.v, b0h, av10);
                av11 = mfma16(A1H.v, b1l, av11); av11 = mfma16(A1L.v, b1h, av11); av11 = mfma16(A1H.v, b1h, av11);
            }
        }

        // ---- net2: grad_phi (frags from LDS) -------------------------------
        f32x4 af00 = (f32x4){0.f, 0.f, 0.f, 0.f};
        f32x4 af01 = af00, af10 = af00, af11 = af00;
        {
            const float* bg = pb1 + 4 * g;
            const float* wg = pW2 + 4 * g;
            int fb0 = 32 * 256 + lane * 4;      // net2 frag base in sfr
            #pragma unroll 1
            for (int s = 0; s < 4; s++) {
                int sb = fb0 + s * 8 * 256;
                bf16x8 p1h0 = *(const bf16x8*)&sfr[sb + 0 * 256];
                bf16x8 p1l0 = *(const bf16x8*)&sfr[sb + 1 * 256];
                bf16x8 p1h1 = *(const bf16x8*)&sfr[sb + 2 * 256];
                bf16x8 p1l1 = *(const bf16x8*)&sfr[sb + 3 * 256];
                f32x4 c0v = *(const f32x4*)(bg + 32 * s);
                f32x4 c1v = *(const f32x4*)(bg + 32 * s + 16);
                f32x4 u00 = c0v, u01 = c1v, u10 = c0v, u11 = c1v;
                u00 = mfma16(p1h0, D0L.v, u00); u00 = mfma16(p1l0, D0H.v, u00); u00 = mfma16(p1h0, D0H.v, u00);
                u01 = mfma16(p1h1, D0L.v, u01); u01 = mfma16(p1l1, D0H.v, u01); u01 = mfma16(p1h1, D0H.v, u01);
                u10 = mfma16(p1h0, D1L.v, u10); u10 = mfma16(p1l0, D1H.v, u10); u10 = mfma16(p1h0, D1H.v, u10);
                u11 = mfma16(p1h1, D1L.v, u11); u11 = mfma16(p1l1, D1H.v, u11); u11 = mfma16(p1h1, D1H.v, u11);
                f32x4 w2q0 = *(const f32x4*)(wg + 32 * s);
                f32x4 w2q1 = *(const f32x4*)(wg + 32 * s + 16);
                b8u A0H, A0L, A1H, A1L;
                split2a(wsech2(w2q0[0], u00[0]), wsech2(w2q0[1], u00[1]), A0H.u[0], A0L.u[0]);
                split2a(wsech2(w2q0[2], u00[2]), wsech2(w2q0[3], u00[3]), A0H.u[1], A0L.u[1]);
                split2a(wsech2(w2q1[0], u01[0]), wsech2(w2q1[1], u01[1]), A0H.u[2], A0L.u[2]);
                split2a(wsech2(w2q1[2], u01[2]), wsech2(w2q1[3], u01[3]), A0H.u[3], A0L.u[3]);
                split2a(wsech2(w2q0[0], u10[0]), wsech2(w2q0[1], u10[1]), A1H.u[0], A1L.u[0]);
                split2a(wsech2(w2q0[2], u10[2]), wsech2(w2q0[3], u10[3]), A1H.u[1], A1L.u[1]);
                split2a(wsech2(w2q1[0], u11[0]), wsech2(w2q1[1], u11[1]), A1H.u[2], A1L.u[2]);
                split2a(wsech2(w2q1[2], u11[2]), wsech2(w2q1[3], u11[3]), A1H.u[3], A1L.u[3]);
                bf16x8 b0h = *(const bf16x8*)&sfr[sb + 4 * 256];
                bf16x8 b0l = *(const bf16x8*)&sfr[sb + 5 * 256];
                bf16x8 b1h = *(const bf16x8*)&sfr[sb + 6 * 256];
                bf16x8 b1l = *(const bf16x8*)&sfr[sb + 7 * 256];
                af00 = mfma16(A0H.v, b0l, af00); af00 = mfma16(A0L.v, b0h, af00); af00 = mfma16(A0H.v, b0h, af00);
                af01 = mfma16(A0H.v, b1l, af01); af01 = mfma16(A0L.v, b1h, af01); af01 = mfma16(A0H.v, b1h, af01);
                af10 = mfma16(A1H.v, b0l, af10); af10 = mfma16(A1L.v, b0h, af10); af10 = mfma16(A1H.v, b0h, af10);
                af11 = mfma16(A1H.v, b1l, af11); af11 = mfma16(A1L.v, b1h, af11); af11 = mfma16(A1H.v, b1h, af11);
            }
        }

        // ---- write both halves ---------------------------------------------
        #pragma unroll
        for (int r = 0; r < 4; r++) {
            int rp = rbase + 4 * g + r;
            unsigned int e2 = partner[rp];
            float fsw = (e2 & ENC_ZF) ? 0.f : ((e2 & ENC_SEC) ? 1.f : -1.f);
            if (rp < B) {
                out[(size_t)rp * DD + m]      = av00[r] + fsw * af00[r];
                out[(size_t)rp * DD + 16 + m] = av01[r] + fsw * af01[r];
            } else {
                int tw = rp - B;
                if (tw < 6) {
                    tripg[tw * DD + m]      = af00[r];
                    tripg[tw * DD + 16 + m] = af01[r];
                }
            }
            int rq = rbase + 16 + 4 * g + r;
            unsigned int e3 = partner[rq];
            float fsq = (e3 & ENC_ZF) ? 0.f : ((e3 & ENC_SEC) ? 1.f : -1.f);
            if (rq < B) {
                out[(size_t)rq * DD + m]      = av10[r] + fsq * af10[r];
                out[(size_t)rq * DD + 16 + m] = av11[r] + fsq * af11[r];
            } else {
                int tw = rq - B;
                if (tw < 6) {
                    tripg[tw * DD + m]      = af10[r];
                    tripg[tw * DD + 16 + m] = af11[r];
                }
            }
        }
    }
}

// ---- Triple combine (identical to R14) ------------------------------------
__global__ void k_triple_combine(
    const int*   __restrict__ perm,
    const float* __restrict__ tripg,
    float* __restrict__ out,
    int np)
{
    int tid = threadIdx.x;
    if (tid >= 3 * DD) return;
    int i = tid >> 5, d = tid & (DD - 1);
    int row = perm[2 * np + i];
    float s = tripg[(2 * i) * DD + d] + tripg[(2 * i + 1) * DD + d];
    out[(size_t)row * DD + d] -= 2.0f * s;
}

extern "C" void kernel_launch(void* const* d_in, const int* in_sizes, int n_in,
                              void* d_out, int out_size, void* d_ws, size_t ws_size,
                              hipStream_t stream) {
    const float* t    = (const float*)d_in[0];
    const float* z    = (const float*)d_in[1];
    const int*   perm = (const int*)  d_in[2];
    const float* vW1  = (const float*)d_in[3];
    const float* vb1  = (const float*)d_in[4];
    const float* vW2  = (const float*)d_in[5];
    const float* vb2  = (const float*)d_in[6];
    const float* pW1  = (const float*)d_in[7];
    const float* pb1  = (const float*)d_in[8];
    const float* pW2  = (const float*)d_in[9];
    // d_in[10] = pb2: constant, vanishes under grad — unused.

    float* out = (float*)d_out;
    float* ws  = (float*)d_ws;

    int B = in_sizes[2];
    int np, ntr;
    if ((B & 1) == 0) { np = B / 2;       ntr = 0; }
    else              { np = (B - 3) / 2; ntr = 1; }

    int nlog   = B + (ntr ? 6 : 0);
    int ntiles = (nlog + 31) >> 5;           // 32-row tiles
    int npart  = ntiles * 32;

    unsigned int* partner = (unsigned int*)(ws + WS_PART);
    int*          tripS   = (int*)(ws + WS_TRIPS);

    k_prep<<<17, 256, 0, stream>>>(t, vW1, vb1, vW2, pW1, ws);
    k_prep2<<<(np + 255) / 256, 256, 0, stream>>>(perm, partner, tripS,
                                                  np, ntr, B, npart);
    // persistent blocks: 512 blocks (2/CU at 64KB LDS), each loops over tiles
    k_main<<<512, 256, 0, stream>>>(z, ws, partner, vb2, pb1, pW2,
                                    out, ws + WS_TRIPG, B, ntiles);
    if (ntr) {
        k_triple_combine<<<1, 128, 0, stream>>>(perm, ws + WS_TRIPG, out, np);
    }
}

// Round 21
// 52.470 us; speedup vs baseline: 1.1743x; 1.1743x over previous
//
#include <hip/hip_runtime.h>
#include <hip/hip_bf16.h>
#include <math.h>

#define DD 32
#define HH 128

typedef __attribute__((ext_vector_type(8))) __bf16 bf16x8;
typedef __attribute__((ext_vector_type(4))) float  f32x4;

// ---- ws layout (float offsets) — identical to R14 -------------------------
#define WS_TRIPG 0
#define WS_TRIPS 192
#define WS_C0    224
#define WS_FRAG  384
#define WS_PART  16768

#define ENC_ZF  0x40000000u
#define ENC_SEC 0x80000000u

union b8u { bf16x8 v; uint32_t u[4]; };

__device__ __forceinline__ f32x4 mfma16(bf16x8 a, bf16x8 b, f32x4 c) {
    return __builtin_amdgcn_mfma_f32_16x16x32_bf16(a, b, c, 0, 0, 0);
}

// ---- primitives (R14-proven) ----------------------------------------------
__device__ __forceinline__ uint32_t cvtpk(float a, float b) {
    uint32_t r;
    asm("v_cvt_pk_bf16_f32 %0, %1, %2" : "=v"(r) : "v"(a), "v"(b));
    return r;
}
__device__ __forceinline__ float vexp2(float x) {   // 2^x
    float r; asm("v_exp_f32 %0, %1" : "=v"(r) : "v"(x)); return r;
}
__device__ __forceinline__ float vrcp(float x) {    // 1/x approx
    float r; asm("v_rcp_f32 %0, %1" : "=v"(r) : "v"(x)); return r;
}

#define TWO_LOG2E 2.8853900817779268f   // e^{2x} = 2^{x*TWO_LOG2E}

__device__ __forceinline__ float tanh_fast(float x) {   // 1 - 2/(e^{2x}+1)
    float e = vexp2(x * TWO_LOG2E);
    float q = 2.0f * vrcp(e + 1.0f);
    return 1.0f - q;
}
__device__ __forceinline__ float wsech2(float w, float x) { // w*q*(2-q)
    float e = vexp2(x * TWO_LOG2E);
    float q = 2.0f * vrcp(e + 1.0f);
    return w * (q * (2.0f - q));
}

// prep-only split (runs once)
__device__ __forceinline__ void split2(float a, float b,
                                       uint32_t& h, uint32_t& l) {
    __hip_bfloat162 hb = __float22bfloat162_rn(make_float2(a, b));
    uint32_t hu; __builtin_memcpy(&hu, &hb, 4);
    float af = __uint_as_float(hu << 16);
    float bf = __uint_as_float(hu & 0xffff0000u);
    __hip_bfloat162 lb = __float22bfloat162_rn(make_float2(a - af, b - bf));
    uint32_t lu; __builtin_memcpy(&lu, &lb, 4);
    h = hu; l = lu;
}

// ---- Prep 1: c0 + frag table (identical to R14) ---------------------------
// kappa conventions (A and B share kappa -> correct for any hw k-order):
//   GEMM1 (K=32):  kappa1(g,i) = 8g + i
//   GEMM2 (K=128, step s): kappa2(g,s,i) = 16*(2s + (i>>2)) + 4g + (i&3)
__global__ void k_prep(const float* __restrict__ t,
                       const float* __restrict__ vW1,  // (33,128)
                       const float* __restrict__ vb1,  // (128)
                       const float* __restrict__ vW2,  // (128,32)
                       const float* __restrict__ pW1,  // (32,128)
                       float* __restrict__ ws)
{
    int tid = blockIdx.x * 256 + threadIdx.x;
    if (tid < 4096) {
        int f = tid >> 6, lane = tid & 63;
        int g = lane >> 4, m = lane & 15;
        int reg  = f >> 5;          // 0:net1  1:net2
        int s    = (f >> 3) & 3;
        int slot = f & 7;
        bool isLo = slot & 1;
        float v[8];
        if (slot < 4) {             // A-operand (vW1 / pW1), th = 2s+(slot>>1)
            const float* W = reg ? pW1 : vW1;
            int th = 2 * s + (slot >> 1);
            #pragma unroll
            for (int i = 0; i < 8; i++)
                v[i] = W[(8 * g + i) * HH + 16 * th + m];
        } else {                    // B-operand, nt = (slot-4)>>1
            int nt = (slot - 4) >> 1;
            #pragma unroll
            for (int i = 0; i < 8; i++) {
                int kh = 16 * (2 * s + (i >> 2)) + 4 * g + (i & 3);
                v[i] = reg ? pW1[(nt * 16 + m) * HH + kh]
                           : vW2[kh * DD + nt * 16 + m];
            }
        }
        b8u H, L;
        #pragma unroll
        for (int j = 0; j < 4; j++)
            split2(v[2 * j], v[2 * j + 1], H.u[j], L.u[j]);
        *(f32x4*)(ws + WS_FRAG + (size_t)(f * 64 + lane) * 4) =
            isLo ? *(f32x4*)&L : *(f32x4*)&H;
    } else if (tid < 4096 + HH) {
        int k = tid - 4096;
        ws[WS_C0 + k] = vb1[k] + t[0] * vW1[DD * HH + k];
    }
}

// ---- Prep 2: row-centric partner[] (identical to R14) ---------------------
__global__ void k_prep2(const int* __restrict__ perm,
                        unsigned int* __restrict__ partner,
                        int* __restrict__ tripS,
                        int np, int ntr, int B, int npart)
{
    int j = blockIdx.x * 256 + threadIdx.x;
    if (j < np) {
        int a = perm[2 * j], b = perm[2 * j + 1];
        partner[a] = (unsigned int)b;
        partner[b] = (unsigned int)a | ENC_SEC;
    }
    if (j == 0) {
        int base = B;
        if (ntr) {
            for (int i = 0; i < 3; i++)
                partner[perm[2 * np + i]] = ENC_ZF;
            for (int ti = 0; ti < 6; ti++) {
                int i3 = ti >> 1, r3 = ti & 1;
                int j3 = r3 + ((r3 >= i3) ? 1 : 0);
                tripS[ti] = perm[2 * np + i3];
                partner[B + ti] = (unsigned int)perm[2 * np + j3];
            }
            base = B + 6;
        }
        for (int q = base; q < npart; q++) partner[q] = ENC_ZF;
    }
}

// ---- Main: R14 structure; inputs/activations bf16-hi only -----------------
// Weight-lo kept (precomputed). GEMM1 = Wl*Zh + Wh*Zh; GEMM2 = Ah*Bl + Ah*Bh.
// 64 MFMAs/tile (was 96); all input/activation converts are single cvt_pk.
__global__ __launch_bounds__(256) void k_main(
    const float* __restrict__ z,
    const float* __restrict__ ws,
    const unsigned int* __restrict__ partner,
    const float* __restrict__ vb2,
    const float* __restrict__ pb1,
    const float* __restrict__ pW2,
    float* __restrict__ out,
    float* __restrict__ tripg,
    int B, int ntiles)
{
    int lane = threadIdx.x & 63;
    int tt   = blockIdx.x * 4 + (threadIdx.x >> 6);
    if (tt >= ntiles) return;
    int g = lane >> 4, m = lane & 15;
    const int* tripS = (const int*)(ws + WS_TRIPS);

    int rbase = tt * 32;
    int il0 = rbase + m, il1 = rbase + 16 + m;

    unsigned int e0 = partner[il0];
    unsigned int e1 = partner[il1];
    int pi0 = (int)(e0 & 0x3FFFFFFFu);
    int pi1 = (int)(e1 & 0x3FFFFFFFu);
    int is0 = il0, is1 = il1;
    if (il0 >= B) { int ti = il0 - B; is0 = (ti < 6) ? tripS[ti] : 0; }
    if (il1 >= B) { int ti = il1 - B; is1 = (ti < 6) ? tripS[ti] : 0; }
    float fs0 = (e0 & ENC_ZF) ? 0.f : ((e0 & ENC_SEC) ? 1.f : -1.f);
    float fs1 = (e1 & ENC_ZF) ? 0.f : ((e1 & ENC_SEC) ? 1.f : -1.f);

    // issue all 8 z loads up front
    const float* pz0 = z + (size_t)is0 * DD + 8 * g;
    const float* pp0 = z + (size_t)pi0 * DD + 8 * g;
    const float* pz1 = z + (size_t)is1 * DD + 8 * g;
    const float* pp1 = z + (size_t)pi1 * DD + 8 * g;
    f32x4 zi00 = *(const f32x4*)pz0, zi01 = *(const f32x4*)(pz0 + 4);
    f32x4 zp00 = *(const f32x4*)pp0, zp01 = *(const f32x4*)(pp0 + 4);
    f32x4 zi10 = *(const f32x4*)pz1, zi11 = *(const f32x4*)(pz1 + 4);
    f32x4 zp10 = *(const f32x4*)pp1, zp11 = *(const f32x4*)(pp1 + 4);
    float vb20 = vb2[m], vb21 = vb2[16 + m];

    // bf16-hi only (single cvt_pk per pair)
    b8u Z0H, D0H, Z1H, D1H;
    Z0H.u[0] = cvtpk(zi00[0], zi00[1]); Z0H.u[1] = cvtpk(zi00[2], zi00[3]);
    Z0H.u[2] = cvtpk(zi01[0], zi01[1]); Z0H.u[3] = cvtpk(zi01[2], zi01[3]);
    Z1H.u[0] = cvtpk(zi10[0], zi10[1]); Z1H.u[1] = cvtpk(zi10[2], zi10[3]);
    Z1H.u[2] = cvtpk(zi11[0], zi11[1]); Z1H.u[3] = cvtpk(zi11[2], zi11[3]);
    D0H.u[0] = cvtpk(-fs0 * (zi00[0] - zp00[0]), -fs0 * (zi00[1] - zp00[1]));
    D0H.u[1] = cvtpk(-fs0 * (zi00[2] - zp00[2]), -fs0 * (zi00[3] - zp00[3]));
    D0H.u[2] = cvtpk(-fs0 * (zi01[0] - zp01[0]), -fs0 * (zi01[1] - zp01[1]));
    D0H.u[3] = cvtpk(-fs0 * (zi01[2] - zp01[2]), -fs0 * (zi01[3] - zp01[3]));
    D1H.u[0] = cvtpk(-fs1 * (zi10[0] - zp10[0]), -fs1 * (zi10[1] - zp10[1]));
    D1H.u[1] = cvtpk(-fs1 * (zi10[2] - zp10[2]), -fs1 * (zi10[3] - zp10[3]));
    D1H.u[2] = cvtpk(-fs1 * (zi11[0] - zp11[0]), -fs1 * (zi11[1] - zp11[1]));
    D1H.u[3] = cvtpk(-fs1 * (zi11[2] - zp11[2]), -fs1 * (zi11[3] - zp11[3]));

    // ---- net1: dz_dt -------------------------------------------------------
    f32x4 av00 = (f32x4){vb20, vb20, vb20, vb20};
    f32x4 av01 = (f32x4){vb21, vb21, vb21, vb21};
    f32x4 av10 = av00, av11 = av01;
    {
        const float* fa = ws + WS_FRAG + (size_t)lane * 4;  // A frags
        const float* fb = fa + 4 * 256;                     // B frags
        const float* cg = ws + WS_C0 + 4 * g;
        #pragma unroll 1
        for (int s = 0; s < 4; s++, fa += 8 * 256, fb += 8 * 256) {
            bf16x8 w1h0 = *(const bf16x8*)(fa + 0 * 256);
            bf16x8 w1l0 = *(const bf16x8*)(fa + 1 * 256);
            bf16x8 w1h1 = *(const bf16x8*)(fa + 2 * 256);
            bf16x8 w1l1 = *(const bf16x8*)(fa + 3 * 256);
            f32x4 c0v = *(const f32x4*)(cg + 32 * s);
            f32x4 c1v = *(const f32x4*)(cg + 32 * s + 16);
            f32x4 u00 = c0v, u01 = c1v, u10 = c0v, u11 = c1v;
            u00 = mfma16(w1l0, Z0H.v, u00); u00 = mfma16(w1h0, Z0H.v, u00);
            u01 = mfma16(w1l1, Z0H.v, u01); u01 = mfma16(w1h1, Z0H.v, u01);
            u10 = mfma16(w1l0, Z1H.v, u10); u10 = mfma16(w1h0, Z1H.v, u10);
            u11 = mfma16(w1l1, Z1H.v, u11); u11 = mfma16(w1h1, Z1H.v, u11);
            b8u A0H, A1H;
            A0H.u[0] = cvtpk(tanh_fast(u00[0]), tanh_fast(u00[1]));
            A0H.u[1] = cvtpk(tanh_fast(u00[2]), tanh_fast(u00[3]));
            A0H.u[2] = cvtpk(tanh_fast(u01[0]), tanh_fast(u01[1]));
            A0H.u[3] = cvtpk(tanh_fast(u01[2]), tanh_fast(u01[3]));
            A1H.u[0] = cvtpk(tanh_fast(u10[0]), tanh_fast(u10[1]));
            A1H.u[1] = cvtpk(tanh_fast(u10[2]), tanh_fast(u10[3]));
            A1H.u[2] = cvtpk(tanh_fast(u11[0]), tanh_fast(u11[1]));
            A1H.u[3] = cvtpk(tanh_fast(u11[2]), tanh_fast(u11[3]));
            bf16x8 b0h = *(const bf16x8*)(fb + 0 * 256);
            bf16x8 b0l = *(const bf16x8*)(fb + 1 * 256);
            bf16x8 b1h = *(const bf16x8*)(fb + 2 * 256);
            bf16x8 b1l = *(const bf16x8*)(fb + 3 * 256);
            av00 = mfma16(A0H.v, b0l, av00); av00 = mfma16(A0H.v, b0h, av00);
            av01 = mfma16(A0H.v, b1l, av01); av01 = mfma16(A0H.v, b1h, av01);
            av10 = mfma16(A1H.v, b0l, av10); av10 = mfma16(A1H.v, b0h, av10);
            av11 = mfma16(A1H.v, b1l, av11); av11 = mfma16(A1H.v, b1h, av11);
        }
    }

    // ---- net2: grad_phi ----------------------------------------------------
    f32x4 af00 = (f32x4){0.f, 0.f, 0.f, 0.f};
    f32x4 af01 = af00, af10 = af00, af11 = af00;
    {
        const float* fa = ws + WS_FRAG + (size_t)(32 * 64 + lane) * 4;
        const float* fb = fa + 4 * 256;
        const float* bg = pb1 + 4 * g;
        const float* wg = pW2 + 4 * g;
        #pragma unroll 1
        for (int s = 0; s < 4; s++, fa += 8 * 256, fb += 8 * 256) {
            bf16x8 p1h0 = *(const bf16x8*)(fa + 0 * 256);
            bf16x8 p1l0 = *(const bf16x8*)(fa + 1 * 256);
            bf16x8 p1h1 = *(const bf16x8*)(fa + 2 * 256);
            bf16x8 p1l1 = *(const bf16x8*)(fa + 3 * 256);
            f32x4 c0v = *(const f32x4*)(bg + 32 * s);
            f32x4 c1v = *(const f32x4*)(bg + 32 * s + 16);
            f32x4 u00 = c0v, u01 = c1v, u10 = c0v, u11 = c1v;
            u00 = mfma16(p1l0, D0H.v, u00); u00 = mfma16(p1h0, D0H.v, u00);
            u01 = mfma16(p1l1, D0H.v, u01); u01 = mfma16(p1h1, D0H.v, u01);
            u10 = mfma16(p1l0, D1H.v, u10); u10 = mfma16(p1h0, D1H.v, u10);
            u11 = mfma16(p1l1, D1H.v, u11); u11 = mfma16(p1h1, D1H.v, u11);
            f32x4 w2q0 = *(const f32x4*)(wg + 32 * s);
            f32x4 w2q1 = *(const f32x4*)(wg + 32 * s + 16);
            b8u A0H, A1H;
            A0H.u[0] = cvtpk(wsech2(w2q0[0], u00[0]), wsech2(w2q0[1], u00[1]));
            A0H.u[1] = cvtpk(wsech2(w2q0[2], u00[2]), wsech2(w2q0[3], u00[3]));
            A0H.u[2] = cvtpk(wsech2(w2q1[0], u01[0]), wsech2(w2q1[1], u01[1]));
            A0H.u[3] = cvtpk(wsech2(w2q1[2], u01[2]), wsech2(w2q1[3], u01[3]));
            A1H.u[0] = cvtpk(wsech2(w2q0[0], u10[0]), wsech2(w2q0[1], u10[1]));
            A1H.u[1] = cvtpk(wsech2(w2q0[2], u10[2]), wsech2(w2q0[3], u10[3]));
            A1H.u[2] = cvtpk(wsech2(w2q1[0], u11[0]), wsech2(w2q1[1], u11[1]));
            A1H.u[3] = cvtpk(wsech2(w2q1[2], u11[2]), wsech2(w2q1[3], u11[3]));
            bf16x8 b0h = *(const bf16x8*)(fb + 0 * 256);
            bf16x8 b0l = *(const bf16x8*)(fb + 1 * 256);
            bf16x8 b1h = *(const bf16x8*)(fb + 2 * 256);
            bf16x8 b1l = *(const bf16x8*)(fb + 3 * 256);
            af00 = mfma16(A0H.v, b0l, af00); af00 = mfma16(A0H.v, b0h, af00);
            af01 = mfma16(A0H.v, b1l, af01); af01 = mfma16(A0H.v, b1h, af01);
            af10 = mfma16(A1H.v, b0l, af10); af10 = mfma16(A1H.v, b0h, af10);
            af11 = mfma16(A1H.v, b1l, af11); af11 = mfma16(A1H.v, b1h, af11);
        }
    }

    // ---- write both halves -------------------------------------------------
    #pragma unroll
    for (int r = 0; r < 4; r++) {
        int rp = rbase + 4 * g + r;
        unsigned int e2 = partner[rp];
        float fsw = (e2 & ENC_ZF) ? 0.f : ((e2 & ENC_SEC) ? 1.f : -1.f);
        if (rp < B) {
            out[(size_t)rp * DD + m]      = av00[r] + fsw * af00[r];
            out[(size_t)rp * DD + 16 + m] = av01[r] + fsw * af01[r];
        } else {
            int tw = rp - B;
            if (tw < 6) {
                tripg[tw * DD + m]      = af00[r];
                tripg[tw * DD + 16 + m] = af01[r];
            }
        }
        int rq = rbase + 16 + 4 * g + r;
        unsigned int e3 = partner[rq];
        float fsq = (e3 & ENC_ZF) ? 0.f : ((e3 & ENC_SEC) ? 1.f : -1.f);
        if (rq < B) {
            out[(size_t)rq * DD + m]      = av10[r] + fsq * af10[r];
            out[(size_t)rq * DD + 16 + m] = av11[r] + fsq * af11[r];
        } else {
            int tw = rq - B;
            if (tw < 6) {
                tripg[tw * DD + m]      = af10[r];
                tripg[tw * DD + 16 + m] = af11[r];
            }
        }
    }
}

// ---- Triple combine (identical to R14) ------------------------------------
__global__ void k_triple_combine(
    const int*   __restrict__ perm,
    const float* __restrict__ tripg,
    float* __restrict__ out,
    int np)
{
    int tid = threadIdx.x;
    if (tid >= 3 * DD) return;
    int i = tid >> 5, d = tid & (DD - 1);
    int row = perm[2 * np + i];
    float s = tripg[(2 * i) * DD + d] + tripg[(2 * i + 1) * DD + d];
    out[(size_t)row * DD + d] -= 2.0f * s;
}

extern "C" void kernel_launch(void* const* d_in, const int* in_sizes, int n_in,
                              void* d_out, int out_size, void* d_ws, size_t ws_size,
                              hipStream_t stream) {
    const float* t    = (const float*)d_in[0];
    const float* z    = (const float*)d_in[1];
    const int*   perm = (const int*)  d_in[2];
    const float* vW1  = (const float*)d_in[3];
    const float* vb1  = (const float*)d_in[4];
    const float* vW2  = (const float*)d_in[5];
    const float* vb2  = (const float*)d_in[6];
    const float* pW1  = (const float*)d_in[7];
    const float* pb1  = (const float*)d_in[8];
    const float* pW2  = (const float*)d_in[9];
    // d_in[10] = pb2: constant, vanishes under grad — unused.

    float* out = (float*)d_out;
    float* ws  = (float*)d_ws;

    int B = in_sizes[2];
    int np, ntr;
    if ((B & 1) == 0) { np = B / 2;       ntr = 0; }
    else              { np = (B - 3) / 2; ntr = 1; }

    int nlog   = B + (ntr ? 6 : 0);
    int ntiles = (nlog + 31) >> 5;           // 32-row tiles
    int npart  = ntiles * 32;

    unsigned int* partner = (unsigned int*)(ws + WS_PART);
    int*          tripS   = (int*)(ws + WS_TRIPS);

    k_prep<<<17, 256, 0, stream>>>(t, vW1, vb1, vW2, pW1, ws);
    k_prep2<<<(np + 255) / 256, 256, 0, stream>>>(perm, partner, tripS,
                                                  np, ntr, B, npart);
    k_main<<<(ntiles + 3) / 4, 256, 0, stream>>>(z, ws, partner, vb2, pb1,
                                                 pW2, out, ws + WS_TRIPG,
                                                 B, ntiles);
    if (ntr) {
        k_triple_combine<<<1, 128, 0, stream>>>(perm, ws + WS_TRIPG, out, np);
    }
}

// Round 22
// 48.586 us; speedup vs baseline: 1.2682x; 1.0799x over previous
//
#include <hip/hip_runtime.h>
#include <hip/hip_bf16.h>
#include <math.h>

#define DD 32
#define HH 128

typedef __attribute__((ext_vector_type(8))) __bf16 bf16x8;
typedef __attribute__((ext_vector_type(4))) float  f32x4;

// ---- ws layout (float offsets) — identical to R14/R21 ---------------------
#define WS_TRIPG 0
#define WS_TRIPS 192
#define WS_C0    224
#define WS_FRAG  384
#define WS_PART  16768

#define ENC_ZF  0x40000000u
#define ENC_SEC 0x80000000u

union b8u { bf16x8 v; uint32_t u[4]; };

__device__ __forceinline__ f32x4 mfma16(bf16x8 a, bf16x8 b, f32x4 c) {
    return __builtin_amdgcn_mfma_f32_16x16x32_bf16(a, b, c, 0, 0, 0);
}

// ---- primitives (R14-proven) ----------------------------------------------
__device__ __forceinline__ uint32_t cvtpk(float a, float b) {
    uint32_t r;
    asm("v_cvt_pk_bf16_f32 %0, %1, %2" : "=v"(r) : "v"(a), "v"(b));
    return r;
}
__device__ __forceinline__ float vexp2(float x) {   // 2^x
    float r; asm("v_exp_f32 %0, %1" : "=v"(r) : "v"(x)); return r;
}
__device__ __forceinline__ float vrcp(float x) {    // 1/x approx
    float r; asm("v_rcp_f32 %0, %1" : "=v"(r) : "v"(x)); return r;
}

#define TWO_LOG2E 2.8853900817779268f   // e^{2x} = 2^{x*TWO_LOG2E}

__device__ __forceinline__ float tanh_fast(float x) {   // 1 - 2/(e^{2x}+1)
    float e = vexp2(x * TWO_LOG2E);
    float q = 2.0f * vrcp(e + 1.0f);
    return 1.0f - q;
}
__device__ __forceinline__ float wsech2(float w, float x) { // w*q*(2-q)
    float e = vexp2(x * TWO_LOG2E);
    float q = 2.0f * vrcp(e + 1.0f);
    return w * (q * (2.0f - q));
}

// prep-only split (runs once)
__device__ __forceinline__ void split2(float a, float b,
                                       uint32_t& h, uint32_t& l) {
    __hip_bfloat162 hb = __float22bfloat162_rn(make_float2(a, b));
    uint32_t hu; __builtin_memcpy(&hu, &hb, 4);
    float af = __uint_as_float(hu << 16);
    float bf = __uint_as_float(hu & 0xffff0000u);
    __hip_bfloat162 lb = __float22bfloat162_rn(make_float2(a - af, b - bf));
    uint32_t lu; __builtin_memcpy(&lu, &lb, 4);
    h = hu; l = lu;
}

// ---- Prep 1: c0 + frag table (identical to R14; L-frags unused now) -------
// kappa conventions (A and B share kappa -> correct for any hw k-order):
//   GEMM1 (K=32):  kappa1(g,i) = 8g + i
//   GEMM2 (K=128, step s): kappa2(g,s,i) = 16*(2s + (i>>2)) + 4g + (i&3)
__global__ void k_prep(const float* __restrict__ t,
                       const float* __restrict__ vW1,  // (33,128)
                       const float* __restrict__ vb1,  // (128)
                       const float* __restrict__ vW2,  // (128,32)
                       const float* __restrict__ pW1,  // (32,128)
                       float* __restrict__ ws)
{
    int tid = blockIdx.x * 256 + threadIdx.x;
    if (tid < 4096) {
        int f = tid >> 6, lane = tid & 63;
        int g = lane >> 4, m = lane & 15;
        int reg  = f >> 5;          // 0:net1  1:net2
        int s    = (f >> 3) & 3;
        int slot = f & 7;
        bool isLo = slot & 1;
        float v[8];
        if (slot < 4) {             // A-operand (vW1 / pW1), th = 2s+(slot>>1)
            const float* W = reg ? pW1 : vW1;
            int th = 2 * s + (slot >> 1);
            #pragma unroll
            for (int i = 0; i < 8; i++)
                v[i] = W[(8 * g + i) * HH + 16 * th + m];
        } else {                    // B-operand, nt = (slot-4)>>1
            int nt = (slot - 4) >> 1;
            #pragma unroll
            for (int i = 0; i < 8; i++) {
                int kh = 16 * (2 * s + (i >> 2)) + 4 * g + (i & 3);
                v[i] = reg ? pW1[(nt * 16 + m) * HH + kh]
                           : vW2[kh * DD + nt * 16 + m];
            }
        }
        b8u H, L;
        #pragma unroll
        for (int j = 0; j < 4; j++)
            split2(v[2 * j], v[2 * j + 1], H.u[j], L.u[j]);
        *(f32x4*)(ws + WS_FRAG + (size_t)(f * 64 + lane) * 4) =
            isLo ? *(f32x4*)&L : *(f32x4*)&H;
    } else if (tid < 4096 + HH) {
        int k = tid - 4096;
        ws[WS_C0 + k] = vb1[k] + t[0] * vW1[DD * HH + k];
    }
}

// ---- Prep 2: row-centric partner[] (identical to R14) ---------------------
__global__ void k_prep2(const int* __restrict__ perm,
                        unsigned int* __restrict__ partner,
                        int* __restrict__ tripS,
                        int np, int ntr, int B, int npart)
{
    int j = blockIdx.x * 256 + threadIdx.x;
    if (j < np) {
        int a = perm[2 * j], b = perm[2 * j + 1];
        partner[a] = (unsigned int)b;
        partner[b] = (unsigned int)a | ENC_SEC;
    }
    if (j == 0) {
        int base = B;
        if (ntr) {
            for (int i = 0; i < 3; i++)
                partner[perm[2 * np + i]] = ENC_ZF;
            for (int ti = 0; ti < 6; ti++) {
                int i3 = ti >> 1, r3 = ti & 1;
                int j3 = r3 + ((r3 >= i3) ? 1 : 0);
                tripS[ti] = perm[2 * np + i3];
                partner[B + ti] = (unsigned int)perm[2 * np + j3];
            }
            base = B + 6;
        }
        for (int q = base; q < npart; q++) partner[q] = ENC_ZF;
    }
}

// ---- Main: pure-bf16 MFMA (H-frags only) ----------------------------------
// GEMM1 = Wh*Zh; GEMM2 = Ah*Bh. 32 MFMAs/tile, 8 frag loads/s-iter -> 4.
// Precision: all operands bf16-RNE; measured error floor unchanged through
// R21's equivalent input-side quantization.
__global__ __launch_bounds__(256) void k_main(
    const float* __restrict__ z,
    const float* __restrict__ ws,
    const unsigned int* __restrict__ partner,
    const float* __restrict__ vb2,
    const float* __restrict__ pb1,
    const float* __restrict__ pW2,
    float* __restrict__ out,
    float* __restrict__ tripg,
    int B, int ntiles)
{
    int lane = threadIdx.x & 63;
    int tt   = blockIdx.x * 4 + (threadIdx.x >> 6);
    if (tt >= ntiles) return;
    int g = lane >> 4, m = lane & 15;
    const int* tripS = (const int*)(ws + WS_TRIPS);

    int rbase = tt * 32;
    int il0 = rbase + m, il1 = rbase + 16 + m;

    unsigned int e0 = partner[il0];
    unsigned int e1 = partner[il1];
    int pi0 = (int)(e0 & 0x3FFFFFFFu);
    int pi1 = (int)(e1 & 0x3FFFFFFFu);
    int is0 = il0, is1 = il1;
    if (il0 >= B) { int ti = il0 - B; is0 = (ti < 6) ? tripS[ti] : 0; }
    if (il1 >= B) { int ti = il1 - B; is1 = (ti < 6) ? tripS[ti] : 0; }
    float fs0 = (e0 & ENC_ZF) ? 0.f : ((e0 & ENC_SEC) ? 1.f : -1.f);
    float fs1 = (e1 & ENC_ZF) ? 0.f : ((e1 & ENC_SEC) ? 1.f : -1.f);

    // issue all 8 z loads up front
    const float* pz0 = z + (size_t)is0 * DD + 8 * g;
    const float* pp0 = z + (size_t)pi0 * DD + 8 * g;
    const float* pz1 = z + (size_t)is1 * DD + 8 * g;
    const float* pp1 = z + (size_t)pi1 * DD + 8 * g;
    f32x4 zi00 = *(const f32x4*)pz0, zi01 = *(const f32x4*)(pz0 + 4);
    f32x4 zp00 = *(const f32x4*)pp0, zp01 = *(const f32x4*)(pp0 + 4);
    f32x4 zi10 = *(const f32x4*)pz1, zi11 = *(const f32x4*)(pz1 + 4);
    f32x4 zp10 = *(const f32x4*)pp1, zp11 = *(const f32x4*)(pp1 + 4);
    float vb20 = vb2[m], vb21 = vb2[16 + m];

    // bf16-hi only (single cvt_pk per pair)
    b8u Z0H, D0H, Z1H, D1H;
    Z0H.u[0] = cvtpk(zi00[0], zi00[1]); Z0H.u[1] = cvtpk(zi00[2], zi00[3]);
    Z0H.u[2] = cvtpk(zi01[0], zi01[1]); Z0H.u[3] = cvtpk(zi01[2], zi01[3]);
    Z1H.u[0] = cvtpk(zi10[0], zi10[1]); Z1H.u[1] = cvtpk(zi10[2], zi10[3]);
    Z1H.u[2] = cvtpk(zi11[0], zi11[1]); Z1H.u[3] = cvtpk(zi11[2], zi11[3]);
    D0H.u[0] = cvtpk(-fs0 * (zi00[0] - zp00[0]), -fs0 * (zi00[1] - zp00[1]));
    D0H.u[1] = cvtpk(-fs0 * (zi00[2] - zp00[2]), -fs0 * (zi00[3] - zp00[3]));
    D0H.u[2] = cvtpk(-fs0 * (zi01[0] - zp01[0]), -fs0 * (zi01[1] - zp01[1]));
    D0H.u[3] = cvtpk(-fs0 * (zi01[2] - zp01[2]), -fs0 * (zi01[3] - zp01[3]));
    D1H.u[0] = cvtpk(-fs1 * (zi10[0] - zp10[0]), -fs1 * (zi10[1] - zp10[1]));
    D1H.u[1] = cvtpk(-fs1 * (zi10[2] - zp10[2]), -fs1 * (zi10[3] - zp10[3]));
    D1H.u[2] = cvtpk(-fs1 * (zi11[0] - zp11[0]), -fs1 * (zi11[1] - zp11[1]));
    D1H.u[3] = cvtpk(-fs1 * (zi11[2] - zp11[2]), -fs1 * (zi11[3] - zp11[3]));

    // ---- net1: dz_dt (Wh*Zh only) ------------------------------------------
    f32x4 av00 = (f32x4){vb20, vb20, vb20, vb20};
    f32x4 av01 = (f32x4){vb21, vb21, vb21, vb21};
    f32x4 av10 = av00, av11 = av01;
    {
        const float* fa = ws + WS_FRAG + (size_t)lane * 4;  // A frags (H at slot0/2)
        const float* fb = fa + 4 * 256;                     // B frags (H at slot4/6)
        const float* cg = ws + WS_C0 + 4 * g;
        #pragma unroll 1
        for (int s = 0; s < 4; s++, fa += 8 * 256, fb += 8 * 256) {
            bf16x8 w1h0 = *(const bf16x8*)(fa + 0 * 256);
            bf16x8 w1h1 = *(const bf16x8*)(fa + 2 * 256);
            f32x4 c0v = *(const f32x4*)(cg + 32 * s);
            f32x4 c1v = *(const f32x4*)(cg + 32 * s + 16);
            f32x4 u00 = c0v, u01 = c1v, u10 = c0v, u11 = c1v;
            u00 = mfma16(w1h0, Z0H.v, u00);
            u01 = mfma16(w1h1, Z0H.v, u01);
            u10 = mfma16(w1h0, Z1H.v, u10);
            u11 = mfma16(w1h1, Z1H.v, u11);
            b8u A0H, A1H;
            A0H.u[0] = cvtpk(tanh_fast(u00[0]), tanh_fast(u00[1]));
            A0H.u[1] = cvtpk(tanh_fast(u00[2]), tanh_fast(u00[3]));
            A0H.u[2] = cvtpk(tanh_fast(u01[0]), tanh_fast(u01[1]));
            A0H.u[3] = cvtpk(tanh_fast(u01[2]), tanh_fast(u01[3]));
            A1H.u[0] = cvtpk(tanh_fast(u10[0]), tanh_fast(u10[1]));
            A1H.u[1] = cvtpk(tanh_fast(u10[2]), tanh_fast(u10[3]));
            A1H.u[2] = cvtpk(tanh_fast(u11[0]), tanh_fast(u11[1]));
            A1H.u[3] = cvtpk(tanh_fast(u11[2]), tanh_fast(u11[3]));
            bf16x8 b0h = *(const bf16x8*)(fb + 0 * 256);
            bf16x8 b1h = *(const bf16x8*)(fb + 2 * 256);
            av00 = mfma16(A0H.v, b0h, av00);
            av01 = mfma16(A0H.v, b1h, av01);
            av10 = mfma16(A1H.v, b0h, av10);
            av11 = mfma16(A1H.v, b1h, av11);
        }
    }

    // ---- net2: grad_phi (Ah*Bh only) ---------------------------------------
    f32x4 af00 = (f32x4){0.f, 0.f, 0.f, 0.f};
    f32x4 af01 = af00, af10 = af00, af11 = af00;
    {
        const float* fa = ws + WS_FRAG + (size_t)(32 * 64 + lane) * 4;
        const float* fb = fa + 4 * 256;
        const float* bg = pb1 + 4 * g;
        const float* wg = pW2 + 4 * g;
        #pragma unroll 1
        for (int s = 0; s < 4; s++, fa += 8 * 256, fb += 8 * 256) {
            bf16x8 p1h0 = *(const bf16x8*)(fa + 0 * 256);
            bf16x8 p1h1 = *(const bf16x8*)(fa + 2 * 256);
            f32x4 c0v = *(const f32x4*)(bg + 32 * s);
            f32x4 c1v = *(const f32x4*)(bg + 32 * s + 16);
            f32x4 u00 = c0v, u01 = c1v, u10 = c0v, u11 = c1v;
            u00 = mfma16(p1h0, D0H.v, u00);
            u01 = mfma16(p1h1, D0H.v, u01);
            u10 = mfma16(p1h0, D1H.v, u10);
            u11 = mfma16(p1h1, D1H.v, u11);
            f32x4 w2q0 = *(const f32x4*)(wg + 32 * s);
            f32x4 w2q1 = *(const f32x4*)(wg + 32 * s + 16);
            b8u A0H, A1H;
            A0H.u[0] = cvtpk(wsech2(w2q0[0], u00[0]), wsech2(w2q0[1], u00[1]));
            A0H.u[1] = cvtpk(wsech2(w2q0[2], u00[2]), wsech2(w2q0[3], u00[3]));
            A0H.u[2] = cvtpk(wsech2(w2q1[0], u01[0]), wsech2(w2q1[1], u01[1]));
            A0H.u[3] = cvtpk(wsech2(w2q1[2], u01[2]), wsech2(w2q1[3], u01[3]));
            A1H.u[0] = cvtpk(wsech2(w2q0[0], u10[0]), wsech2(w2q0[1], u10[1]));
            A1H.u[1] = cvtpk(wsech2(w2q0[2], u10[2]), wsech2(w2q0[3], u10[3]));
            A1H.u[2] = cvtpk(wsech2(w2q1[0], u11[0]), wsech2(w2q1[1], u11[1]));
            A1H.u[3] = cvtpk(wsech2(w2q1[2], u11[2]), wsech2(w2q1[3], u11[3]));
            bf16x8 b0h = *(const bf16x8*)(fb + 0 * 256);
            bf16x8 b1h = *(const bf16x8*)(fb + 2 * 256);
            af00 = mfma16(A0H.v, b0h, af00);
            af01 = mfma16(A0H.v, b1h, af01);
            af10 = mfma16(A1H.v, b0h, af10);
            af11 = mfma16(A1H.v, b1h, af11);
        }
    }

    // ---- write both halves -------------------------------------------------
    #pragma unroll
    for (int r = 0; r < 4; r++) {
        int rp = rbase + 4 * g + r;
        unsigned int e2 = partner[rp];
        float fsw = (e2 & ENC_ZF) ? 0.f : ((e2 & ENC_SEC) ? 1.f : -1.f);
        if (rp < B) {
            out[(size_t)rp * DD + m]      = av00[r] + fsw * af00[r];
            out[(size_t)rp * DD + 16 + m] = av01[r] + fsw * af01[r];
        } else {
            int tw = rp - B;
            if (tw < 6) {
                tripg[tw * DD + m]      = af00[r];
                tripg[tw * DD + 16 + m] = af01[r];
            }
        }
        int rq = rbase + 16 + 4 * g + r;
        unsigned int e3 = partner[rq];
        float fsq = (e3 & ENC_ZF) ? 0.f : ((e3 & ENC_SEC) ? 1.f : -1.f);
        if (rq < B) {
            out[(size_t)rq * DD + m]      = av10[r] + fsq * af10[r];
            out[(size_t)rq * DD + 16 + m] = av11[r] + fsq * af11[r];
        } else {
            int tw = rq - B;
            if (tw < 6) {
                tripg[tw * DD + m]      = af10[r];
                tripg[tw * DD + 16 + m] = af11[r];
            }
        }
    }
}

// ---- Triple combine (identical to R14) ------------------------------------
__global__ void k_triple_combine(
    const int*   __restrict__ perm,
    const float* __restrict__ tripg,
    float* __restrict__ out,
    int np)
{
    int tid = threadIdx.x;
    if (tid >= 3 * DD) return;
    int i = tid >> 5, d = tid & (DD - 1);
    int row = perm[2 * np + i];
    float s = tripg[(2 * i) * DD + d] + tripg[(2 * i + 1) * DD + d];
    out[(size_t)row * DD + d] -= 2.0f * s;
}

extern "C" void kernel_launch(void* const* d_in, const int* in_sizes, int n_in,
                              void* d_out, int out_size, void* d_ws, size_t ws_size,
                              hipStream_t stream) {
    const float* t    = (const float*)d_in[0];
    const float* z    = (const float*)d_in[1];
    const int*   perm = (const int*)  d_in[2];
    const float* vW1  = (const float*)d_in[3];
    const float* vb1  = (const float*)d_in[4];
    const float* vW2  = (const float*)d_in[5];
    const float* vb2  = (const float*)d_in[6];
    const float* pW1  = (const float*)d_in[7];
    const float* pb1  = (const float*)d_in[8];
    const float* pW2  = (const float*)d_in[9];
    // d_in[10] = pb2: constant, vanishes under grad — unused.

    float* out = (float*)d_out;
    float* ws  = (float*)d_ws;

    int B = in_sizes[2];
    int np, ntr;
    if ((B & 1) == 0) { np = B / 2;       ntr = 0; }
    else              { np = (B - 3) / 2; ntr = 1; }

    int nlog   = B + (ntr ? 6 : 0);
    int ntiles = (nlog + 31) >> 5;           // 32-row tiles
    int npart  = ntiles * 32;

    unsigned int* partner = (unsigned int*)(ws + WS_PART);
    int*          tripS   = (int*)(ws + WS_TRIPS);

    k_prep<<<17, 256, 0, stream>>>(t, vW1, vb1, vW2, pW1, ws);
    k_prep2<<<(np + 255) / 256, 256, 0, stream>>>(perm, partner, tripS,
                                                  np, ntr, B, npart);
    k_main<<<(ntiles + 3) / 4, 256, 0, stream>>>(z, ws, partner, vb2, pb1,
                                                 pW2, out, ws + WS_TRIPG,
                                                 B, ntiles);
    if (ntr) {
        k_triple_combine<<<1, 128, 0, stream>>>(perm, ws + WS_TRIPG, out, np);
    }
}

// Round 23
// 34.500 us; speedup vs baseline: 1.7860x; 1.4083x over previous
//
#include <hip/hip_runtime.h>
#include <hip/hip_bf16.h>
#include <math.h>

#define DD 32
#define HH 128

typedef __attribute__((ext_vector_type(8))) __bf16 bf16x8;
typedef __attribute__((ext_vector_type(4))) float  f32x4;
typedef __attribute__((ext_vector_type(2))) int    i32x2;

// ---- ws layout (float offsets) -------------------------------------------
// [0,192)    tripg : 6 x 32 raw triple gradients
// [224,352)  c0    : vb1[kh] + t * vW1[32][kh]
// [384,16768) frags: 64 frags, lane-major (frag*64+lane)*4 floats
#define WS_TRIPG 0
#define WS_C0    224
#define WS_FRAG  384

union b8u { bf16x8 v; uint32_t u[4]; };

__device__ __forceinline__ f32x4 mfma16(bf16x8 a, bf16x8 b, f32x4 c) {
    return __builtin_amdgcn_mfma_f32_16x16x32_bf16(a, b, c, 0, 0, 0);
}

// ---- primitives (R14/R22-proven) ------------------------------------------
__device__ __forceinline__ uint32_t cvtpk(float a, float b) {
    uint32_t r;
    asm("v_cvt_pk_bf16_f32 %0, %1, %2" : "=v"(r) : "v"(a), "v"(b));
    return r;
}
__device__ __forceinline__ float vexp2(float x) {   // 2^x
    float r; asm("v_exp_f32 %0, %1" : "=v"(r) : "v"(x)); return r;
}
__device__ __forceinline__ float vrcp(float x) {    // 1/x approx
    float r; asm("v_rcp_f32 %0, %1" : "=v"(r) : "v"(x)); return r;
}

#define TWO_LOG2E 2.8853900817779268f   // e^{2x} = 2^{x*TWO_LOG2E}

__device__ __forceinline__ float tanh_fast(float x) {   // 1 - 2/(e^{2x}+1)
    float e = vexp2(x * TWO_LOG2E);
    float q = 2.0f * vrcp(e + 1.0f);
    return 1.0f - q;
}
__device__ __forceinline__ float wsech2(float w, float x) { // w*q*(2-q)
    float e = vexp2(x * TWO_LOG2E);
    float q = 2.0f * vrcp(e + 1.0f);
    return w * (q * (2.0f - q));
}

// prep-only split (runs once)
__device__ __forceinline__ void split2(float a, float b,
                                       uint32_t& h, uint32_t& l) {
    __hip_bfloat162 hb = __float22bfloat162_rn(make_float2(a, b));
    uint32_t hu; __builtin_memcpy(&hu, &hb, 4);
    float af = __uint_as_float(hu << 16);
    float bf = __uint_as_float(hu & 0xffff0000u);
    __hip_bfloat162 lb = __float22bfloat162_rn(make_float2(a - af, b - bf));
    uint32_t lu; __builtin_memcpy(&lu, &lb, 4);
    h = hu; l = lu;
}

// ---- Prep: c0 + frag table (identical to R14/R22) -------------------------
// kappa conventions (A and B share kappa -> correct for any hw k-order):
//   GEMM1 (K=32):  kappa1(g,i) = 8g + i
//   GEMM2 (K=128, step s): kappa2(g,s,i) = 16*(2s + (i>>2)) + 4g + (i&3)
__global__ void k_prep(const float* __restrict__ t,
                       const float* __restrict__ vW1,  // (33,128)
                       const float* __restrict__ vb1,  // (128)
                       const float* __restrict__ vW2,  // (128,32)
                       const float* __restrict__ pW1,  // (32,128)
                       float* __restrict__ ws)
{
    int tid = blockIdx.x * 256 + threadIdx.x;
    if (tid < 4096) {
        int f = tid >> 6, lane = tid & 63;
        int g = lane >> 4, m = lane & 15;
        int reg  = f >> 5;          // 0:net1  1:net2
        int s    = (f >> 3) & 3;
        int slot = f & 7;
        bool isLo = slot & 1;
        float v[8];
        if (slot < 4) {             // A-operand (vW1 / pW1), th = 2s+(slot>>1)
            const float* W = reg ? pW1 : vW1;
            int th = 2 * s + (slot >> 1);
            #pragma unroll
            for (int i = 0; i < 8; i++)
                v[i] = W[(8 * g + i) * HH + 16 * th + m];
        } else {                    // B-operand, nt = (slot-4)>>1
            int nt = (slot - 4) >> 1;
            #pragma unroll
            for (int i = 0; i < 8; i++) {
                int kh = 16 * (2 * s + (i >> 2)) + 4 * g + (i & 3);
                v[i] = reg ? pW1[(nt * 16 + m) * HH + kh]
                           : vW2[kh * DD + nt * 16 + m];
            }
        }
        b8u H, L;
        #pragma unroll
        for (int j = 0; j < 4; j++)
            split2(v[2 * j], v[2 * j + 1], H.u[j], L.u[j]);
        *(f32x4*)(ws + WS_FRAG + (size_t)(f * 64 + lane) * 4) =
            isLo ? *(f32x4*)&L : *(f32x4*)&H;
    } else if (tid < 4096 + HH) {
        int k = tid - 4096;
        ws[WS_C0 + k] = vb1[k] + t[0] * vW1[DD * HH + k];
    }
}

// ---- decode work item p -> rows (a,b) and mode ----------------------------
// mode 0: normal pair (force -G/+G); 1: zero-force pseudo-pair (dzdt only);
// 2: grad-extra (write G to tripg); 3: out of range.
__device__ __forceinline__ int decode(int p, int np, const int* perm,
                                      int& a, int& b) {
    if (p < np) {
        i32x2 pr = *(const i32x2*)(perm + 2 * p);
        a = pr[0]; b = pr[1];
        return 0;
    } else if (p == np) {                 // triple rows t0,t1: dzdt only
        a = perm[2 * np]; b = perm[2 * np + 1];
        return 1;
    } else if (p == np + 1) {             // triple row t2 (both sides same)
        a = perm[2 * np + 2]; b = a;
        return 1;
    } else if (p < np + 8) {              // 6 ordered triple grads
        int k = p - np - 2;
        int i3 = k >> 1, r3 = k & 1;
        int j3 = r3 + ((r3 >= i3) ? 1 : 0);
        a = perm[2 * np + i3]; b = perm[2 * np + j3];
        return 2;
    }
    a = 0; b = 0;
    return 3;
}

// ---- Main: pair-centric fused dzdt + force --------------------------------
// Wave owns 16 pairs: dzdt for both rows (sets A,B), grad ONCE per pair
// (set D). out[a] = dzdt_a - G, out[b] = dzdt_b + G (rows disjoint: perm
// is a permutation). Bitwise-identical math to R22 per output element.
__global__ __launch_bounds__(256) void k_main(
    const float* __restrict__ z,
    const float* __restrict__ ws,
    const int*   __restrict__ perm,
    const float* __restrict__ vb2,
    const float* __restrict__ pb1,
    const float* __restrict__ pW2,
    float* __restrict__ out,
    float* __restrict__ tripg,
    int np, int ntiles)
{
    int lane = threadIdx.x & 63;
    int tt   = blockIdx.x * 4 + (threadIdx.x >> 6);
    if (tt >= ntiles) return;
    int g = lane >> 4, m = lane & 15;

    int pbase = tt * 16;
    int a, b;
    decode(pbase + m, np, perm, a, b);

    // load both rows of the pair (issued up front)
    const float* pa = z + (size_t)a * DD + 8 * g;
    const float* pb = z + (size_t)b * DD + 8 * g;
    f32x4 za0 = *(const f32x4*)pa, za1 = *(const f32x4*)(pa + 4);
    f32x4 zb0 = *(const f32x4*)pb, zb1 = *(const f32x4*)(pb + 4);
    float vb20 = vb2[m], vb21 = vb2[16 + m];

    // bf16 packs: ZA (a-rows), ZB (b-rows), D = a-b
    b8u ZA, ZB, DH;
    ZA.u[0] = cvtpk(za0[0], za0[1]); ZA.u[1] = cvtpk(za0[2], za0[3]);
    ZA.u[2] = cvtpk(za1[0], za1[1]); ZA.u[3] = cvtpk(za1[2], za1[3]);
    ZB.u[0] = cvtpk(zb0[0], zb0[1]); ZB.u[1] = cvtpk(zb0[2], zb0[3]);
    ZB.u[2] = cvtpk(zb1[0], zb1[1]); ZB.u[3] = cvtpk(zb1[2], zb1[3]);
    DH.u[0] = cvtpk(za0[0] - zb0[0], za0[1] - zb0[1]);
    DH.u[1] = cvtpk(za0[2] - zb0[2], za0[3] - zb0[3]);
    DH.u[2] = cvtpk(za1[0] - zb1[0], za1[1] - zb1[1]);
    DH.u[3] = cvtpk(za1[2] - zb1[2], za1[3] - zb1[3]);

    // ---- net1: dz_dt for sets A and B (shared frag loads) ------------------
    f32x4 avA0 = (f32x4){vb20, vb20, vb20, vb20};
    f32x4 avA1 = (f32x4){vb21, vb21, vb21, vb21};
    f32x4 avB0 = avA0, avB1 = avA1;
    {
        const float* fa = ws + WS_FRAG + (size_t)lane * 4;
        const float* fb = fa + 4 * 256;
        const float* cg = ws + WS_C0 + 4 * g;
        #pragma unroll 1
        for (int s = 0; s < 4; s++, fa += 8 * 256, fb += 8 * 256) {
            bf16x8 w1h0 = *(const bf16x8*)(fa + 0 * 256);
            bf16x8 w1h1 = *(const bf16x8*)(fa + 2 * 256);
            f32x4 c0v = *(const f32x4*)(cg + 32 * s);
            f32x4 c1v = *(const f32x4*)(cg + 32 * s + 16);
            f32x4 uA0 = c0v, uA1 = c1v, uB0 = c0v, uB1 = c1v;
            uA0 = mfma16(w1h0, ZA.v, uA0);
            uA1 = mfma16(w1h1, ZA.v, uA1);
            uB0 = mfma16(w1h0, ZB.v, uB0);
            uB1 = mfma16(w1h1, ZB.v, uB1);
            b8u AA, AB;
            AA.u[0] = cvtpk(tanh_fast(uA0[0]), tanh_fast(uA0[1]));
            AA.u[1] = cvtpk(tanh_fast(uA0[2]), tanh_fast(uA0[3]));
            AA.u[2] = cvtpk(tanh_fast(uA1[0]), tanh_fast(uA1[1]));
            AA.u[3] = cvtpk(tanh_fast(uA1[2]), tanh_fast(uA1[3]));
            AB.u[0] = cvtpk(tanh_fast(uB0[0]), tanh_fast(uB0[1]));
            AB.u[1] = cvtpk(tanh_fast(uB0[2]), tanh_fast(uB0[3]));
            AB.u[2] = cvtpk(tanh_fast(uB1[0]), tanh_fast(uB1[1]));
            AB.u[3] = cvtpk(tanh_fast(uB1[2]), tanh_fast(uB1[3]));
            bf16x8 b0h = *(const bf16x8*)(fb + 0 * 256);
            bf16x8 b1h = *(const bf16x8*)(fb + 2 * 256);
            avA0 = mfma16(AA.v, b0h, avA0);
            avA1 = mfma16(AA.v, b1h, avA1);
            avB0 = mfma16(AB.v, b0h, avB0);
            avB1 = mfma16(AB.v, b1h, avB1);
        }
    }

    // ---- net2: grad_phi on D (once per pair) -------------------------------
    f32x4 af0 = (f32x4){0.f, 0.f, 0.f, 0.f}, af1 = af0;
    {
        const float* fa = ws + WS_FRAG + (size_t)(32 * 64 + lane) * 4;
        const float* fb = fa + 4 * 256;
        const float* bg = pb1 + 4 * g;
        const float* wg = pW2 + 4 * g;
        #pragma unroll 1
        for (int s = 0; s < 4; s++, fa += 8 * 256, fb += 8 * 256) {
            bf16x8 p1h0 = *(const bf16x8*)(fa + 0 * 256);
            bf16x8 p1h1 = *(const bf16x8*)(fa + 2 * 256);
            f32x4 c0v = *(const f32x4*)(bg + 32 * s);
            f32x4 c1v = *(const f32x4*)(bg + 32 * s + 16);
            f32x4 v0 = c0v, v1 = c1v;
            v0 = mfma16(p1h0, DH.v, v0);
            v1 = mfma16(p1h1, DH.v, v1);
            f32x4 w2q0 = *(const f32x4*)(wg + 32 * s);
            f32x4 w2q1 = *(const f32x4*)(wg + 32 * s + 16);
            b8u GH;
            GH.u[0] = cvtpk(wsech2(w2q0[0], v0[0]), wsech2(w2q0[1], v0[1]));
            GH.u[1] = cvtpk(wsech2(w2q0[2], v0[2]), wsech2(w2q0[3], v0[3]));
            GH.u[2] = cvtpk(wsech2(w2q1[0], v1[0]), wsech2(w2q1[1], v1[1]));
            GH.u[3] = cvtpk(wsech2(w2q1[2], v1[2]), wsech2(w2q1[3], v1[3]));
            bf16x8 b0h = *(const bf16x8*)(fb + 0 * 256);
            bf16x8 b1h = *(const bf16x8*)(fb + 2 * 256);
            af0 = mfma16(GH.v, b0h, af0);
            af1 = mfma16(GH.v, b1h, af1);
        }
    }

    // ---- write: lane (g,m) holds pair p2=pbase+4g+r, cols m / 16+m ---------
    #pragma unroll
    for (int r = 0; r < 4; r++) {
        int p2 = pbase + 4 * g + r;
        int aw, bw;
        int mode = decode(p2, np, perm, aw, bw);
        if (mode == 0) {
            out[(size_t)aw * DD + m]      = avA0[r] - af0[r];
            out[(size_t)aw * DD + 16 + m] = avA1[r] - af1[r];
            out[(size_t)bw * DD + m]      = avB0[r] + af0[r];
            out[(size_t)bw * DD + 16 + m] = avB1[r] + af1[r];
        } else if (mode == 1) {
            out[(size_t)aw * DD + m]      = avA0[r];
            out[(size_t)aw * DD + 16 + m] = avA1[r];
            out[(size_t)bw * DD + m]      = avB0[r];
            out[(size_t)bw * DD + 16 + m] = avB1[r];
        } else if (mode == 2) {
            int k = p2 - np - 2;
            tripg[k * DD + m]      = af0[r];
            tripg[k * DD + 16 + m] = af1[r];
        }
    }
}

// ---- Triple combine: out[t_i] -= 2*(G(2i) + G(2i+1)) ----------------------
__global__ void k_triple_combine(
    const int*   __restrict__ perm,
    const float* __restrict__ tripg,
    float* __restrict__ out,
    int np)
{
    int tid = threadIdx.x;
    if (tid >= 3 * DD) return;
    int i = tid >> 5, d = tid & (DD - 1);
    int row = perm[2 * np + i];
    float s = tripg[(2 * i) * DD + d] + tripg[(2 * i + 1) * DD + d];
    out[(size_t)row * DD + d] -= 2.0f * s;
}

extern "C" void kernel_launch(void* const* d_in, const int* in_sizes, int n_in,
                              void* d_out, int out_size, void* d_ws, size_t ws_size,
                              hipStream_t stream) {
    const float* t    = (const float*)d_in[0];
    const float* z    = (const float*)d_in[1];
    const int*   perm = (const int*)  d_in[2];
    const float* vW1  = (const float*)d_in[3];
    const float* vb1  = (const float*)d_in[4];
    const float* vW2  = (const float*)d_in[5];
    const float* vb2  = (const float*)d_in[6];
    const float* pW1  = (const float*)d_in[7];
    const float* pb1  = (const float*)d_in[8];
    const float* pW2  = (const float*)d_in[9];
    // d_in[10] = pb2: constant, vanishes under grad — unused.

    float* out = (float*)d_out;
    float* ws  = (float*)d_ws;

    int B = in_sizes[2];
    int np, ntr;
    if ((B & 1) == 0) { np = B / 2;       ntr = 0; }
    else              { np = (B - 3) / 2; ntr = 1; }

    // work items: np pairs + (triple: 2 ZF pseudo-pairs + 6 grad extras)
    int nwork  = np + (ntr ? 8 : 0);
    int ntiles = (nwork + 15) >> 4;

    k_prep<<<17, 256, 0, stream>>>(t, vW1, vb1, vW2, pW1, ws);
    k_main<<<(ntiles + 3) / 4, 256, 0, stream>>>(z, ws, perm, vb2, pb1, pW2,
                                                 out, ws + WS_TRIPG,
                                                 np, ntiles);
    if (ntr) {
        k_triple_combine<<<1, 128, 0, stream>>>(perm, ws + WS_TRIPG, out, np);
    }
}